// Round 9
// baseline (274.338 us; speedup 1.0000x reference)
//
#include <hip/hip_runtime.h>
#include <hip/hip_bf16.h>
#include <cstdint>
#include <cstddef>

#define B_ 2
#define N_ 2048
#define D_ 1024
#define H_ 16
#define DH_ 64
#define XYROWS 4095   /* N + (N-1) */
#define NL 12         /* self + 11 tree neighbors */
#define QKVN 3072     /* packed Q|K|V projection width */

typedef __attribute__((ext_vector_type(8))) short bf16x8;
typedef __attribute__((ext_vector_type(4))) float f32x4;

__device__ __forceinline__ float asf(unsigned int u) {
    union { unsigned int i; float f; } v; v.i = u; return v.f;
}
__device__ __forceinline__ unsigned short f2bf(float f) {
    union { float f; unsigned int i; } v; v.f = f;
    unsigned int u = v.i;
    unsigned int r = u + 0x7FFFu + ((u >> 16) & 1u);   // RNE
    return (unsigned short)(r >> 16);
}

// load 8 bf16 (16B) -> 8 fp32
__device__ __forceinline__ void ld8(const unsigned short* p, float* o) {
    uint4 u = *(const uint4*)p;
    o[0] = asf(u.x << 16); o[1] = asf(u.x & 0xffff0000u);
    o[2] = asf(u.y << 16); o[3] = asf(u.y & 0xffff0000u);
    o[4] = asf(u.z << 16); o[5] = asf(u.z & 0xffff0000u);
    o[6] = asf(u.w << 16); o[7] = asf(u.w & 0xffff0000u);
}

// async global->LDS 16B per lane; lds base wave-uniform, HW scatters lane l
// to base + l*16.
__device__ __forceinline__ void gload_lds16(const unsigned short* g, unsigned short* l) {
    __builtin_amdgcn_global_load_lds(
        (const __attribute__((address_space(1))) unsigned int*)g,
        (__attribute__((address_space(3))) unsigned int*)l,
        16, 0, 0);
}

// ---- fused prep: build xy (bf16) + convert all four weight matrices ----
__global__ void prep_kernel(const float* __restrict__ q, const float* __restrict__ y,
                            const float* __restrict__ Wq, const float* __restrict__ Wk,
                            const float* __restrict__ Wv, const float* __restrict__ Wo,
                            unsigned short* __restrict__ xy,
                            unsigned short* __restrict__ wqkv, unsigned short* __restrict__ wob) {
    int c = blockIdx.x * blockDim.x + threadIdx.x;   // chunk of 8 elems
    constexpr int TOTAL_XY = B_ * XYROWS * (D_ / 8); // 1048320
    constexpr int TOTAL_W  = 4 * 131072;             // 524288
    if (c >= TOTAL_XY + TOTAL_W) return;
    const float* src;
    unsigned short* dst;
    if (c < TOTAL_XY) {
        int col8 = (c & (D_ / 8 - 1)) * 8;
        int rg = c >> 7;                              // global row 0..B*4095-1
        int b = (rg >= XYROWS) ? 1 : 0;
        int r = rg - b * XYROWS;
        if (r < N_) src = q + ((size_t)b * N_ + r) * D_ + col8;
        else        src = y + ((size_t)b * (N_ - 1) + (r - N_)) * D_ + col8;
        dst = xy + (size_t)rg * D_ + col8;
    } else {
        int idx = c - TOTAL_XY;
        int which = idx >> 17;
        int sub = idx & 131071;
        const float* w = (which == 0) ? Wq : (which == 1) ? Wk : (which == 2) ? Wv : Wo;
        src = w + (size_t)sub * 8;
        dst = ((which < 3) ? (wqkv + (size_t)which * D_ * D_) : wob) + (size_t)sub * 8;
    }
    float4 a = *(const float4*)(src);
    float4 bb = *(const float4*)(src + 4);
    union { unsigned short us[8]; uint4 u4; } o;
    o.us[0] = f2bf(a.x);  o.us[1] = f2bf(a.y);  o.us[2] = f2bf(a.z);  o.us[3] = f2bf(a.w);
    o.us[4] = f2bf(bb.x); o.us[5] = f2bf(bb.y); o.us[6] = f2bf(bb.z); o.us[7] = f2bf(bb.w);
    *(uint4*)(dst) = o.u4;
}

// --------------------------- bf16 GEMM: C = A @ W^T -----------------------
// A: M x 1024 bf16 row-major; W: Nn x 1024 bf16 row-major.
// Split operand paths (AITER-style, HIP-expressible):
//  * A: global_load_lds w16, XOR-swizzled, DOUBLE-BUFFERED LDS (2 x BM x 64),
//    ONE barrier per K-iter — staging for iter k+1 issues right after the
//    barrier and flies under iter k's MFMAs; next barrier = just-in-time drain.
//  * B (weights, L2-hot): direct global->VGPR fragment loads, register
//    double-buffered, no LDS round-trip, no barrier dependency.
// This halves the LDS pipe (R8 accounting: 36us LDS vs 22us MFMA per CU).
// *** gridDim.x MUST be a multiple of 8 ***: XCD = linear-block-id % 8 pins
// each x-tile's A-slice to one XCD L2 (R5: grid.x=43 -> 8x A-fetch).
// Stores: PLAIN scalar (R7: NT scalar stores broke L2 write-combining).
// QSKIP: skip Q columns (col0<1024) on row tiles holding only y-positions.
template<int BM, bool OUTF32, bool BIAS, bool QSKIP>
__global__ __launch_bounds__(256, 2)
void gemm_bt(const unsigned short* __restrict__ A, const unsigned short* __restrict__ W,
             void* __restrict__ Cv, const float* __restrict__ bias, int M, int Nn) {
    constexpr int K = 1024, BK = 64, NIT = K / BK;
    constexpr int IM = BM / 32;          // mfma row-tiles per wave
    __shared__ __align__(16) unsigned short la[2][BM * 64];

    int row0 = blockIdx.x * BM;
    if (row0 >= M) return;                  // grid.x padded to a multiple of 8
    int col0 = blockIdx.y * 128;
    if (QSKIP && col0 < 1024) {
        int t = blockIdx.x;                 // y-only row tiles for BM=128:
        if ((t >= 16 && t <= 30) || t >= 48) return;
    }
    int tid = threadIdx.x;
    int wave = tid >> 6, lane = tid & 63;
    int wm = wave >> 1, wn = wave & 1;
    int q4 = lane >> 4, r = lane & 15;

    // A staging: lane l supplies row l/8 of its segment; fetched chunk is
    // XOR-swizzled by the row's low 3 bits (0 bank conflicts on read-back).
    int rsub = lane >> 3;                         // 0..7
    int csw = ((lane & 7) ^ rsub) * 8;            // swizzled source chunk col

    // B fragment base for this lane (per j add j*16 rows; per ks add ks*32 cols)
    const unsigned short* wp = W + (size_t)(col0 + wn * 64 + r) * K + q4 * 8;

    f32x4 acc[IM][4];
    f32x4 zero = {0.f, 0.f, 0.f, 0.f};
#pragma unroll
    for (int i = 0; i < IM; i++)
#pragma unroll
        for (int j = 0; j < 4; j++) acc[i][j] = zero;

    bf16x8 bfv[2][2][4];                          // [buf][ks][j]

    auto stageA = [&](int k0, int buf) {
#pragma unroll
        for (int p = 0; p < IM; p++) {            // 4*IM = BM/8 segments
            int seg = wave * IM + p;
            int ar = row0 + seg * 8 + rsub; if (ar >= M) ar = M - 1;
            gload_lds16(A + (size_t)ar * K + k0 + csw, &la[buf][seg * 512]);
        }
    };
    auto loadB = [&](int k0, int buf) {
#pragma unroll
        for (int ks = 0; ks < 2; ks++)
#pragma unroll
            for (int j = 0; j < 4; j++)
                bfv[buf][ks][j] = *(const bf16x8*)(wp + (size_t)(j * 16) * K + k0 + ks * 32);
    };

    stageA(0, 0);
    loadB(0, 0);
#pragma unroll
    for (int it = 0; it < NIT; it++) {
        int cur = it & 1;
        __syncthreads();                          // drains A[cur] staging (+B[cur])
        if (it + 1 < NIT) {                       // prefetch flies under compute
            stageA((it + 1) * BK, cur ^ 1);
            loadB((it + 1) * BK, cur ^ 1);
        }
#pragma unroll
        for (int ks = 0; ks < 2; ks++) {
            int cidx = ks * 4 + q4;
            bf16x8 af[IM];
#pragma unroll
            for (int i = 0; i < IM; i++) {
                int rr = wm * (BM / 2) + i * 16 + r;
                af[i] = *(const bf16x8*)(&la[cur][rr * 64 + ((cidx ^ (rr & 7)) << 3)]);
            }
#pragma unroll
            for (int i = 0; i < IM; i++)
#pragma unroll
                for (int j = 0; j < 4; j++)
                    acc[i][j] = __builtin_amdgcn_mfma_f32_16x16x32_bf16(af[i], bfv[cur][ks][j], acc[i][j], 0, 0, 0);
        }
    }

    float bv[4];
    if (BIAS) {
#pragma unroll
        for (int j = 0; j < 4; j++) bv[j] = bias[col0 + wn * 64 + j * 16 + r];
    }
#pragma unroll
    for (int i = 0; i < IM; i++) {
#pragma unroll
        for (int j = 0; j < 4; j++) {
            int col = col0 + wn * 64 + j * 16 + r;
#pragma unroll
            for (int reg = 0; reg < 4; reg++) {
                int row = row0 + wm * (BM / 2) + i * 16 + q4 * 4 + reg;
                if (row < M) {
                    float v = acc[i][j][reg];
                    if (BIAS) v += bv[j];
                    if (OUTF32)
                        ((float*)Cv)[(size_t)row * Nn + col] = v;
                    else
                        ((unsigned short*)Cv)[(size_t)row * Nn + col] = f2bf(v);
                }
            }
        }
    }
}

// ----------------------- hierarchical sparse attention --------------------
// 4-query groups {4u..4u+3}: pairs share lvl>=2 (9 rows); lvl1 differs per
// pair; self/sibling rows serve both queries of their pair. 15 K/V rows per
// group (vs 2x12), 34 ld8s per 4 queries (vs 52). Softmax is order-invariant
// so slot order is arbitrary but consistent between logit and V phases.
// Block = 256 thr = 2 groups (t>>7), c = t&127 picks 8-dim chunk.
__global__ __launch_bounds__(256)
void attn_kernel(const unsigned short* __restrict__ QKV, unsigned short* __restrict__ O) {
    int t = threadIdx.x;
    int b = blockIdx.y;
    int u = (blockIdx.x << 1) | (t >> 7);    // group index 0..511
    int c = t & 127;
    int n0 = u << 2;

    int rows[15];
    rows[0] = n0; rows[1] = n0 + 1; rows[2] = n0 + 2; rows[3] = n0 + 3;
    rows[4] = 2048 + 2 * u + 1;              // lvl1 of pair A (queries 0,1)
    rows[5] = 2048 + 2 * u;                  // lvl1 of pair B (queries 2,3)
    int cur = (3072 + u) ^ 1;                // lvl2, shared by all 4
    rows[6] = cur;
#pragma unroll
    for (int l = 7; l < 15; l++) { cur = ((cur >> 1) + N_) ^ 1; rows[l] = cur; }

    const unsigned short* base = QKV + (size_t)b * XYROWS * QKVN;
    size_t c8 = (size_t)c * 8;

    float q[4][8];
#pragma unroll
    for (int i = 0; i < 4; i++) ld8(base + (size_t)(n0 + i) * QKVN + c8, q[i]);

    float lg[4][NL];
    float kv[8];

    // rows 0..3: self/sibling for their pair
#pragma unroll
    for (int i = 0; i < 4; i++) {
        ld8(base + (size_t)rows[i] * QKVN + D_ + c8, kv);
        int pa = i & 2, io = i & 1;
        float s0 = 0.f, s1 = 0.f;
#pragma unroll
        for (int e = 0; e < 8; e++) { s0 = fmaf(q[pa][e], kv[e], s0); s1 = fmaf(q[pa + 1][e], kv[e], s1); }
        s0 += __shfl_xor(s0, 1); s1 += __shfl_xor(s1, 1);
        s0 += __shfl_xor(s0, 2); s1 += __shfl_xor(s1, 2);
        s0 += __shfl_xor(s0, 4); s1 += __shfl_xor(s1, 4);
        lg[pa][io] = s0 * 0.125f;            // row is self for q[pa] iff io==0
        lg[pa + 1][io ^ 1] = s1 * 0.125f;
    }
    // rows 4..5: lvl1 per pair -> slot 2
#pragma unroll
    for (int i = 4; i < 6; i++) {
        ld8(base + (size_t)rows[i] * QKVN + D_ + c8, kv);
        int pa = (i == 4) ? 0 : 2;
        float s0 = 0.f, s1 = 0.f;
#pragma unroll
        for (int e = 0; e < 8; e++) { s0 = fmaf(q[pa][e], kv[e], s0); s1 = fmaf(q[pa + 1][e], kv[e], s1); }
        s0 += __shfl_xor(s0, 1); s1 += __shfl_xor(s1, 1);
        s0 += __shfl_xor(s0, 2); s1 += __shfl_xor(s1, 2);
        s0 += __shfl_xor(s0, 4); s1 += __shfl_xor(s1, 4);
        lg[pa][2] = s0 * 0.125f;
        lg[pa + 1][2] = s1 * 0.125f;
    }
    // rows 6..14: shared -> slots 3..11
#pragma unroll
    for (int i = 6; i < 15; i++) {
        ld8(base + (size_t)rows[i] * QKVN + D_ + c8, kv);
        float s0 = 0.f, s1 = 0.f, s2 = 0.f, s3 = 0.f;
#pragma unroll
        for (int e = 0; e < 8; e++) {
            s0 = fmaf(q[0][e], kv[e], s0); s1 = fmaf(q[1][e], kv[e], s1);
            s2 = fmaf(q[2][e], kv[e], s2); s3 = fmaf(q[3][e], kv[e], s3);
        }
        s0 += __shfl_xor(s0, 1); s1 += __shfl_xor(s1, 1); s2 += __shfl_xor(s2, 1); s3 += __shfl_xor(s3, 1);
        s0 += __shfl_xor(s0, 2); s1 += __shfl_xor(s1, 2); s2 += __shfl_xor(s2, 2); s3 += __shfl_xor(s3, 2);
        s0 += __shfl_xor(s0, 4); s1 += __shfl_xor(s1, 4); s2 += __shfl_xor(s2, 4); s3 += __shfl_xor(s3, 4);
        lg[0][i - 3] = s0 * 0.125f; lg[1][i - 3] = s1 * 0.125f;
        lg[2][i - 3] = s2 * 0.125f; lg[3][i - 3] = s3 * 0.125f;
    }

    // softmax per query (weights left unnormalized; fold 1/sum at the end)
    float inv[4];
#pragma unroll
    for (int qi = 0; qi < 4; qi++) {
        float mx = lg[qi][0];
#pragma unroll
        for (int j = 1; j < NL; j++) mx = fmaxf(mx, lg[qi][j]);
        float s = 0.f;
#pragma unroll
        for (int j = 0; j < NL; j++) { lg[qi][j] = __expf(lg[qi][j] - mx); s += lg[qi][j]; }
        inv[qi] = 1.f / s;
    }

    float acc[4][8];
#pragma unroll
    for (int qi = 0; qi < 4; qi++)
#pragma unroll
        for (int e = 0; e < 8; e++) acc[qi][e] = 0.f;

#pragma unroll
    for (int i = 0; i < 4; i++) {
        ld8(base + (size_t)rows[i] * QKVN + 2 * D_ + c8, kv);
        int pa = i & 2, io = i & 1;
        float w0 = lg[pa][io], w1 = lg[pa + 1][io ^ 1];
#pragma unroll
        for (int e = 0; e < 8; e++) {
            acc[pa][e] = fmaf(w0, kv[e], acc[pa][e]);
            acc[pa + 1][e] = fmaf(w1, kv[e], acc[pa + 1][e]);
        }
    }
#pragma unroll
    for (int i = 4; i < 6; i++) {
        ld8(base + (size_t)rows[i] * QKVN + 2 * D_ + c8, kv);
        int pa = (i == 4) ? 0 : 2;
        float w0 = lg[pa][2], w1 = lg[pa + 1][2];
#pragma unroll
        for (int e = 0; e < 8; e++) {
            acc[pa][e] = fmaf(w0, kv[e], acc[pa][e]);
            acc[pa + 1][e] = fmaf(w1, kv[e], acc[pa + 1][e]);
        }
    }
#pragma unroll
    for (int i = 6; i < 15; i++) {
        ld8(base + (size_t)rows[i] * QKVN + 2 * D_ + c8, kv);
#pragma unroll
        for (int qi = 0; qi < 4; qi++) {
            float w = lg[qi][i - 3];
#pragma unroll
            for (int e = 0; e < 8; e++) acc[qi][e] = fmaf(w, kv[e], acc[qi][e]);
        }
    }

#pragma unroll
    for (int qi = 0; qi < 4; qi++) {
        union { unsigned short us[8]; uint4 u4; } o;
#pragma unroll
        for (int e = 0; e < 8; e++) o.us[e] = f2bf(acc[qi][e] * inv[qi]);
        *(uint4*)(O + ((size_t)b * N_ + n0 + qi) * D_ + c8) = o.u4;
    }
}

extern "C" void kernel_launch(void* const* d_in, const int* in_sizes, int n_in,
                              void* d_out, int out_size, void* d_ws, size_t ws_size,
                              hipStream_t stream) {
    const float* query = (const float*)d_in[0];
    // d_in[1] (key), d_in[2] (value) are unused by the reference
    const float* y  = (const float*)d_in[3];
    const float* Wq = (const float*)d_in[4];
    const float* Wk = (const float*)d_in[5];
    const float* Wv = (const float*)d_in[6];
    const float* Wo = (const float*)d_in[7];
    const float* bo = (const float*)d_in[8];
    float* out = (float*)d_out;

    char* ws = (char*)d_ws;
    size_t off = 0;
    auto alloc = [&](size_t bytes) {
        void* p = ws + off; off += (bytes + 255) & ~(size_t)255; return p;
    };
    unsigned short* xy   = (unsigned short*)alloc((size_t)B_ * XYROWS * D_ * 2 + 8192);  // pad: OOB-clamped tile rows
    unsigned short* wqkv = (unsigned short*)alloc((size_t)QKVN * D_ * 2 + 8192);
    unsigned short* wob  = (unsigned short*)alloc((size_t)D_ * D_ * 2 + 8192);
    unsigned short* QKV  = (unsigned short*)alloc((size_t)B_ * XYROWS * QKVN * 2 + 16384);
    unsigned short* At   = (unsigned short*)alloc((size_t)B_ * N_ * D_ * 2);

    // 1. fused prep: xy (bf16) + all weight conversions
    prep_kernel<<<6144, 256, 0, stream>>>(query, y, Wq, Wk, Wv, Wo, xy, wqkv, wob);

    // 2. fused QKV projection, BM=128; grid.x=64 (mult of 8 -> XCD-pinned
    //    A-slices); QSKIP drops Q cols on y-only row tiles.
    {
        dim3 g(64, QKVN / 128);
        gemm_bt<128, false, false, true><<<g, 256, 0, stream>>>(
            xy, wqkv, QKV, nullptr, B_ * XYROWS, QKVN);
    }
    // 3. hierarchical attention: 4-query groups, 2 groups/block
    {
        dim3 g(N_ / 8, B_);
        attn_kernel<<<g, 256, 0, stream>>>(QKV, At);
    }
    // 4. output projection + bias (fp32 out), BM=64 -> grid.x 64 (mult of 8)
    {
        dim3 g((B_ * N_) / 64, D_ / 128);
        gemm_bt<64, true, true, false><<<g, 256, 0, stream>>>(At, wob, out, bo, B_ * N_, D_);
    }
}